// Round 11
// baseline (426.991 us; speedup 1.0000x reference)
//
#include <hip/hip_runtime.h>
#include <cstdint>

// SpikeFP64Sqrt: rows of 64 float pulses (MSB-first fp64 bits) -> sqrt via
// exponent-halving guess + 12 IEEE fp64 Newton iterations -> pulses out.
//
// R10 post-mortem: lean extraction + nt stores in k2 neutral (R7/R9/R10 all
// 420-426us). L3 is memory-side -> nt/plain allocation games wash. Remaining
// untested knob: wave lifetime. R7's waves each process ONE 16KB tile (16
// VMEM instrs) then die -> 16384 short-lived waves/kernel, VMEM queues never
// continuously full. The 6.5TB/s fill kernel is the opposite: few waves,
// each streaming for its whole life.
// R11: persistent grid-stride for both kernels (1024 blocks x 4 waves, 4
// tiles/wave) -- each wave issues 4 back-to-back tile bursts, loop overlaps
// next-tile loads with current-tile consumption. Else R7 verbatim.

#pragma clang fp contract(off)   // no FMA contraction anywhere (bit-exact fp64)

typedef float f32x4 __attribute__((ext_vector_type(4)));

static constexpr uint64_t kSqrt2Mant = 1865452045155277ULL;
static constexpr uint64_t kNanBits   = 0x7FF8000000000000ULL;
static constexpr uint64_t kInfBits   = 0x7FF0000000000000ULL;
static constexpr uint64_t kMantMask  = 0xFFFFFFFFFFFFFULL;

__device__ __forceinline__ uint64_t sqrt_word(uint64_t u) {
  // per-lane fp64 sqrt, bit-exact vs reference
  const double f = __longlong_as_double((long long)u);
  const int e_x    = (int)((u >> 52) & 0x7FF);
  const int e_real = e_x - 1023;                       // 11-bit two's complement
  const long long e_half = ((long long)e_real) >> 1;   // arithmetic shift = floor/2
  const uint64_t mant = ((e_real & 1) != 0) ? kSqrt2Mant : 0ULL;
  const uint64_t ybits = (((uint64_t)(e_half + 1023)) << 52) | mant;
  double y = __longlong_as_double((long long)ybits);
#pragma unroll
  for (int it = 0; it < 12; ++it) {
    y = 0.5 * (y + f / y);                             // IEEE fp64, no contraction
  }
  uint64_t r = (uint64_t)__double_as_longlong(y);
  const bool is_neg    = (u >> 63) != 0;
  const bool m_any     = (u & kMantMask) != 0;
  const bool e_all_one = (e_x == 0x7FF);
  const bool e_is_zero = (e_x == 0);
  if (is_neg) r = kNanBits;                            // same override order as ref
  if (e_all_one && m_any) r = kNanBits;
  if (e_all_one && !m_any && !is_neg) r = kInfBits;
  if (e_is_zero && !m_any) r = 0ULL;
  return r;
}

// ------------- kernel 1 (persistent): pulses -> u64 -> sqrt -> words -------
__global__ __launch_bounds__(256) void spike_sqrt_pack_kernel(
    const float* __restrict__ x, uint64_t* __restrict__ w, int rows) {
  const int lane = threadIdx.x & 63;
  const int wid  = (int)blockIdx.x * 4 + (threadIdx.x >> 6);
  const int totalWaves = (int)gridDim.x * 4;
  const int nTiles = (rows + 63) / 64;                 // 64-row tiles
  const int col = lane ^ 63;   // lane j reads pulse (63-j): ballot bit j == MSB bit j

  for (int tile = wid; tile < nTiles; tile += totalWaves) {
    const long long tileRow0 = (long long)tile * 64;
    uint64_t u = 0;
    if (tileRow0 + 64 <= (long long)rows) {
      const float* base = x + tileRow0 * 64 + col;
#pragma unroll
      for (int b = 0; b < 2; ++b) {
        float v[32];
#pragma unroll
        for (int k = 0; k < 32; ++k)   // 32 nt loads in flight (read-once stream)
          v[k] = __builtin_nontemporal_load(base + (size_t)(b * 32 + k) * 64);
#pragma unroll
        for (int k = 0; k < 32; ++k) {
          unsigned long long m = __ballot(v[k] > 0.5f);
          if (lane == b * 32 + k) u = m;
        }
      }
    } else {
#pragma unroll 4
      for (int rr = 0; rr < 64; ++rr) {
        const long long row = tileRow0 + rr;
        float v = (row < (long long)rows) ? x[row * 64 + col] : 0.0f;
        unsigned long long m = __ballot(v > 0.5f);
        if (lane == rr) u = m;
      }
    }

    const uint64_t r = sqrt_word(u);
    const long long myRow = tileRow0 + lane;
    if (myRow < (long long)rows) w[myRow] = r;         // coalesced dwordx2, 512B/wave
  }
}

// ------------- kernel 2 (persistent): words -> pulse write stream ----------
__global__ __launch_bounds__(256) void spike_unpack_kernel(
    const uint64_t* __restrict__ w, float* __restrict__ out, int rows) {
  const int lane = threadIdx.x & 63;
  const int wid  = (int)blockIdx.x * 4 + (threadIdx.x >> 6);
  const int totalWaves = (int)gridDim.x * 4;
  const int nTiles = (rows + 63) / 64;
  const int grp = lane >> 4;
  const int c0  = (lane & 15) * 4;                     // pulse column of o.x

  for (int tile = wid; tile < nTiles; tile += totalWaves) {
    const long long tileRow0 = (long long)tile * 64;
    const long long myRow = tileRow0 + lane;
    const uint64_t r = (myRow < (long long)rows) ? w[myRow] : 0ULL;
    const long long rl = (long long)r;

#pragma unroll
    for (int t = 0; t < 16; ++t) {
      const int srcRow = 4 * t + grp;                  // 0..63 within the tile
      const uint64_t b = (uint64_t)__shfl(rl, srcRow, 64);
      f32x4 o;
      o.x = (float)((b >> (63 - c0)) & 1ULL);
      o.y = (float)((b >> (62 - c0)) & 1ULL);
      o.z = (float)((b >> (61 - c0)) & 1ULL);
      o.w = (float)((b >> (60 - c0)) & 1ULL);
      const long long row = tileRow0 + srcRow;
      if (row < (long long)rows) {
        *reinterpret_cast<f32x4*>(out + row * 64 + c0) = o;   // 1KB per instr
      }
    }
  }
}

extern "C" void kernel_launch(void* const* d_in, const int* in_sizes, int n_in,
                              void* d_out, int out_size, void* d_ws, size_t ws_size,
                              hipStream_t stream) {
  const float* x = (const float*)d_in[0];
  float* out = (float*)d_out;
  uint64_t* words = (uint64_t*)d_ws;                   // rows*8 bytes (8MB) scratch
  const int rows = in_sizes[0] / 64;                   // 64 pulses per fp64
  const int nTiles = (rows + 63) / 64;
  const int grid = (nTiles + 3 < 4096) ? (nTiles + 3) / 4 : 1024;  // persistent: <=1024 blocks
  spike_sqrt_pack_kernel<<<grid, 256, 0, stream>>>(x, words, rows);
  spike_unpack_kernel<<<grid, 256, 0, stream>>>(words, out, rows);
}

// Round 12
// 422.151 us; speedup vs baseline: 1.0115x; 1.0115x over previous
//
#include <hip/hip_runtime.h>
#include <cstdint>

// SpikeFP64Sqrt: rows of 64 float pulses (MSB-first fp64 bits) -> sqrt via
// exponent-halving guess + 12 IEEE fp64 Newton iterations -> pulses out.
//
// FINAL (= R7, best measured: 419.7us total). Two-kernel split through an
// 8MB u64 word buffer in d_ws:
//   kernel1: ballot-pack + fp64 sqrt. 268MB nt read stream (read-once; nt
//            avoids evicting the poison-dirty L3 lines -> R8 showed plain
//            loads regress), 8MB write.
//   kernel2: word -> pulse expansion. 8MB cache-resident read, 268MB
//            coalesced dwordx4 write stream.
// Session ledger (R2-R11): split streams > fused (+15-20us); load MLP>=32
// required (R2's serialized loads cost 60us); pack mechanism (ballot vs LDS
// vs shfl_xor), load width (4B vs 16B), store nt policy, extraction
// leanness, and persistent waves are all NEUTRAL within fill jitter.
// Remaining gap to the 536MB/6.3TB/s floor is <6% of bench time; no lever
// tested moves it -> practical memory-bound plateau.

#pragma clang fp contract(off)   // no FMA contraction anywhere (bit-exact fp64)

typedef float f32x4 __attribute__((ext_vector_type(4)));

static constexpr uint64_t kSqrt2Mant = 1865452045155277ULL;
static constexpr uint64_t kNanBits   = 0x7FF8000000000000ULL;
static constexpr uint64_t kInfBits   = 0x7FF0000000000000ULL;
static constexpr uint64_t kMantMask  = 0xFFFFFFFFFFFFFULL;

// ---------------- kernel 1: pulses -> packed u64 -> sqrt -> word buffer ----
__global__ __launch_bounds__(256) void spike_sqrt_pack_kernel(
    const float* __restrict__ x, uint64_t* __restrict__ w, int rows) {
  const int lane   = threadIdx.x & 63;
  const int waveId = (int)blockIdx.x * 4 + (threadIdx.x >> 6);
  const long long waveRow0 = (long long)waveId * 64;
  const int col = lane ^ 63;   // lane j reads pulse (63-j): ballot bit j == MSB-first bit j

  uint64_t u = 0;
  const bool fullWave = (waveRow0 + 64) <= (long long)rows;
  if (fullWave) {
    const float* base = x + waveRow0 * 64 + col;
#pragma unroll
    for (int b = 0; b < 2; ++b) {
      float v[32];
#pragma unroll
      for (int k = 0; k < 32; ++k)   // 32 nt loads in flight (read-once stream)
        v[k] = __builtin_nontemporal_load(base + (size_t)(b * 32 + k) * 64);
#pragma unroll
      for (int k = 0; k < 32; ++k) {
        unsigned long long m = __ballot(v[k] > 0.5f);
        if (lane == b * 32 + k) u = m;
      }
    }
  } else {
#pragma unroll 4
    for (int rr = 0; rr < 64; ++rr) {
      const long long row = waveRow0 + rr;
      float v = (row < (long long)rows) ? x[row * 64 + col] : 0.0f;
      unsigned long long m = __ballot(v > 0.5f);
      if (lane == rr) u = m;
    }
  }

  // ---- per-lane fp64 sqrt, bit-exact vs reference ----
  const double f = __longlong_as_double((long long)u);

  const int e_x    = (int)((u >> 52) & 0x7FF);
  const int e_real = e_x - 1023;                       // 11-bit two's complement
  const long long e_half = ((long long)e_real) >> 1;   // arithmetic shift = floor/2
  const uint64_t mant = ((e_real & 1) != 0) ? kSqrt2Mant : 0ULL;
  const uint64_t ybits = (((uint64_t)(e_half + 1023)) << 52) | mant;
  double y = __longlong_as_double((long long)ybits);

#pragma unroll
  for (int it = 0; it < 12; ++it) {
    y = 0.5 * (y + f / y);                             // IEEE fp64, no contraction
  }

  uint64_t r = (uint64_t)__double_as_longlong(y);
  const bool is_neg    = (u >> 63) != 0;
  const bool m_any     = (u & kMantMask) != 0;
  const bool e_all_one = (e_x == 0x7FF);
  const bool e_is_zero = (e_x == 0);
  if (is_neg) r = kNanBits;                            // same override order as ref
  if (e_all_one && m_any) r = kNanBits;
  if (e_all_one && !m_any && !is_neg) r = kInfBits;
  if (e_is_zero && !m_any) r = 0ULL;

  const long long myRow = waveRow0 + lane;
  if (myRow < (long long)rows) w[myRow] = r;           // coalesced dwordx2, 512B/wave
}

// ---------------- kernel 2: word buffer -> pulse expansion (write stream) --
__global__ __launch_bounds__(256) void spike_unpack_kernel(
    const uint64_t* __restrict__ w, float* __restrict__ out, int rows) {
  const int lane   = threadIdx.x & 63;
  const int waveId = (int)blockIdx.x * 4 + (threadIdx.x >> 6);
  const long long waveRow0 = (long long)waveId * 64;

  const long long myRow = waveRow0 + lane;
  const uint64_t r = (myRow < (long long)rows) ? w[myRow] : 0ULL;
  const long long rl = (long long)r;

#pragma unroll
  for (int t = 0; t < 16; ++t) {
    const int srcRow = 4 * t + (lane >> 4);            // 0..63 within the wave
    const uint64_t b = (uint64_t)__shfl(rl, srcRow, 64);
    const int c0 = (lane & 15) * 4;                    // pulse index of o.x
    f32x4 o;
    o.x = (float)((b >> (63 - c0)) & 1ULL);
    o.y = (float)((b >> (62 - c0)) & 1ULL);
    o.z = (float)((b >> (61 - c0)) & 1ULL);
    o.w = (float)((b >> (60 - c0)) & 1ULL);
    const long long row = waveRow0 + srcRow;
    if (row < (long long)rows) {
      *reinterpret_cast<f32x4*>(out + row * 64 + c0) = o;   // 1KB per instr
    }
  }
}

extern "C" void kernel_launch(void* const* d_in, const int* in_sizes, int n_in,
                              void* d_out, int out_size, void* d_ws, size_t ws_size,
                              hipStream_t stream) {
  const float* x = (const float*)d_in[0];
  float* out = (float*)d_out;
  uint64_t* words = (uint64_t*)d_ws;                   // rows*8 bytes (8MB) scratch
  const int rows = in_sizes[0] / 64;                   // 64 pulses per fp64
  const int grid = (rows + 255) / 256;                 // 4 waves * 64 rows
  spike_sqrt_pack_kernel<<<grid, 256, 0, stream>>>(x, words, rows);
  spike_unpack_kernel<<<grid, 256, 0, stream>>>(words, out, rows);
}